// Round 3
// baseline (73.264 us; speedup 1.0000x reference)
//
#include <hip/hip_runtime.h>
#include <stdint.h>

#define T_LEN 8192
#define NSTEP 8190   // T - 2 interior samples
#define NB 16
#define NCH 256

// ---------------- threefry2x32 (exact JAX cipher) ----------------
__device__ __forceinline__ uint32_t rotl32(uint32_t v, int r) {
  return (v << r) | (v >> (32 - r));
}

__device__ __forceinline__ void tf2x32(uint32_t k0, uint32_t k1, uint32_t x0, uint32_t x1,
                                       uint32_t& o0, uint32_t& o1) {
  uint32_t ks2 = k0 ^ k1 ^ 0x1BD11BDAu;
  x0 += k0; x1 += k1;
#define RR(r) { x0 += x1; x1 = rotl32(x1, (r)); x1 ^= x0; }
  RR(13) RR(15) RR(26) RR(6)   x0 += k1;  x1 += ks2 + 1u;
  RR(17) RR(29) RR(16) RR(24)  x0 += ks2; x1 += k0 + 2u;
  RR(13) RR(15) RR(26) RR(6)   x0 += k0;  x1 += k1 + 3u;
  RR(17) RR(29) RR(16) RR(24)  x0 += k1;  x1 += ks2 + 4u;
  RR(13) RR(15) RR(26) RR(6)   x0 += ks2; x1 += k0 + 5u;
#undef RR
  o0 = x0; o1 = x1;
}

// ---------------- K1: per-step categorical decisions ----------------
// PARTITIONABLE threefry semantics (JAX >= 0.4.36 default):
//   split(key, n)[i]          = full cipher pair threefry2x32(key, (hi32(i), lo32(i)))
//   random_bits(key,32,(m,))  = bits1 ^ bits2 of cipher(key, (0, c)), c = 0..m-1
//                               (_threefry_random_bits_partitionable XORs both words)
// For each (b, step j) record BOTH possible decisions:
//   n  = argmax(log([p,s,p]) + g)         (any state except (2,1))
//   sp = argmax over {1,2} of special row (state (2,1); category 0 has prob 0)
// packed as byte n | (sp<<2).
__global__ __launch_bounds__(256) void k_decide(const float* __restrict__ probs,
                                                uint8_t* __restrict__ dec) {
  int j = blockIdx.x * 256 + threadIdx.x;
  int b = blockIdx.y;
  if (j >= NSTEP) return;

  // batch key b from split(key(42), 16), foldlike: cipher((0,42), (0, b))
  uint32_t kb0, kb1;
  tf2x32(0u, 42u, 0u, (uint32_t)b, kb0, kb1);

  // step key j from split(kb, 8190), foldlike: cipher(kb, (0, j))
  uint32_t s0, s1;
  tf2x32(kb0, kb1, 0u, (uint32_t)j, s0, s1);

  // random_bits(step_key, 32, (3,)): bits[c] = y0 ^ y1 of cipher(sk, (0, c))
  uint32_t bits[3];
  {
    uint32_t y0, y1;
    tf2x32(s0, s1, 0u, 0u, y0, y1); bits[0] = y0 ^ y1;
    tf2x32(s0, s1, 0u, 1u, y0, y1); bits[1] = y0 ^ y1;
    tf2x32(s0, s1, 0u, 2u, y0, y1); bits[2] = y0 ^ y1;
  }

  double g[3];
#pragma unroll
  for (int c = 0; c < 3; ++c) {
    uint32_t k = bits[c] >> 9;                            // 23-bit mantissa sample
    float u = k ? (float)k * 0x1p-23f : 1.17549435e-38f;  // exact JAX uniform value
    g[c] = -log(-log((double)u));
  }

  // logits (f64; JAX uses f32 XLA log — ~1e-7 tie window accepted)
  double lp = log((double)probs[0]);                  // probs[0,0,0] = p
  double ls = log((double)probs[1]);                  // probs[0,0,1] = s
  double l1 = log((double)probs[2 * 9 + 1 * 3 + 1]);  // special row cat 1
  double l2 = log((double)probs[2 * 9 + 1 * 3 + 2]);  // special row cat 2

  double v0 = lp + g[0], v1 = ls + g[1], v2 = lp + g[2];
  int n = 0; double best = v0;
  if (v1 > best) { n = 1; best = v1; }
  if (v2 > best) { n = 2; }
  int sp = (l1 + g[1] >= l2 + g[2]) ? 1 : 2;          // argmax tie -> first (index 1)

  dec[b * NSTEP + j] = (uint8_t)(n | (sp << 2));
}

// ---------------- K2: parallel Markov scan -> idx table ----------------
// State u = p2*3 + p1 in [0,9). Step: j = (u==7) ? spec : norm; u' = (u%3)*3 + j.
// Chunk maps = 9 nibbles in a u64; Hillis-Steele compose scan.
__device__ __forceinline__ uint64_t compose_map(uint64_t f, uint64_t g) {
  // apply f first, then g: out[s] = g[f[s]]
  uint64_t r = 0;
#pragma unroll
  for (int st = 0; st < 9; ++st) {
    uint32_t fs = (uint32_t)((f >> (4 * st)) & 15u);
    uint32_t gs = (uint32_t)((g >> (4 * fs)) & 15u);
    r |= ((uint64_t)gs) << (4 * st);
  }
  return r;
}

__device__ __forceinline__ uint64_t shflup64(uint64_t v, int delta) {
  int lo = __shfl_up((int)(uint32_t)v, delta, 64);
  int hi = __shfl_up((int)(uint32_t)(v >> 32), delta, 64);
  return (((uint64_t)(uint32_t)hi) << 32) | (uint32_t)lo;
}

#define IDENT_MAP 0x876543210ull

__global__ __launch_bounds__(256) void k_scan(const uint8_t* __restrict__ dec,
                                              int* __restrict__ idxbuf) {
  int b = blockIdx.x;
  int tid = threadIdx.x;
  int lane = tid & 63, wave = tid >> 6;
  int begin = tid * 32;
  const uint8_t* row = dec + b * NSTEP;

  // phase 1: build this chunk's 9-state map
  uint64_t M = IDENT_MAP;
#pragma unroll
  for (int t = 0; t < 32; ++t) {
    int step = begin + t;
    if (step < NSTEP) {
      int d = row[step];
      uint32_t n = d & 3u, s = (d >> 2) & 3u;
      uint64_t Mn = 0;
#pragma unroll
      for (int st = 0; st < 9; ++st) {
        uint32_t u = (uint32_t)((M >> (4 * st)) & 15u);
        uint32_t div3 = (u * 11u) >> 5;          // u/3 for u<9
        uint32_t p1 = u - 3u * div3;
        uint32_t jj = (u == 7u) ? s : n;
        Mn |= ((uint64_t)(p1 * 3u + jj)) << (4 * st);
      }
      M = Mn;
    }
  }

  // phase 2a: wave-inclusive scan (compose with earlier lanes)
  uint64_t I = M;
#pragma unroll
  for (int off = 1; off < 64; off <<= 1) {
    uint64_t Mp = shflup64(I, off);
    uint64_t c = compose_map(Mp, I);
    I = (lane >= off) ? c : I;
  }

  __shared__ uint64_t wmap[4];
  if (lane == 63) wmap[wave] = I;
  __syncthreads();

  // phase 2b: exclusive prefix = (prev waves) then (prev lanes in wave)
  uint64_t W = IDENT_MAP;
  for (int w = 0; w < wave; ++w) W = compose_map(W, wmap[w]);
  uint64_t E = shflup64(I, 1);
  if (lane == 0) E = IDENT_MAP;
  uint64_t X = compose_map(W, E);

  int state = (int)((X >> (4 * 4)) & 15u);  // X applied to initial chain state (1,1)=4

  // phase 3: replay chunk, emit idx[b][step+1] = step + j
  int* orow = idxbuf + b * T_LEN;
#pragma unroll
  for (int t = 0; t < 32; ++t) {
    int step = begin + t;
    if (step < NSTEP) {
      int d = row[step];
      uint32_t n = d & 3u, s = (d >> 2) & 3u;
      uint32_t jj = (state == 7) ? s : n;
      uint32_t div3 = ((uint32_t)state * 11u) >> 5;
      uint32_t p1 = (uint32_t)state - 3u * div3;
      state = (int)(p1 * 3u + jj);
      orow[step + 1] = step + (int)jj;
    }
  }
  if (tid == 0) { orow[0] = 0; orow[T_LEN - 1] = T_LEN - 1; }
}

// ---------------- K3: gather ----------------
__global__ __launch_bounds__(256) void k_gather(const float* __restrict__ x,
                                                const int* __restrict__ idxbuf,
                                                float* __restrict__ out) {
  int b = blockIdx.z, i = blockIdx.y;
  int t0 = (blockIdx.x * 256 + threadIdx.x) * 4;
  const int4 id4 = *(const int4*)(idxbuf + b * T_LEN + t0);
  const float* __restrict__ xr = x + ((size_t)(b * NCH + i)) * T_LEN;
  float4 o;
  o.x = xr[id4.x];
  o.y = xr[id4.y];
  o.z = xr[id4.z];
  o.w = xr[id4.w];
  *(float4*)(out + ((size_t)(b * NCH + i)) * T_LEN + t0) = o;
}

extern "C" void kernel_launch(void* const* d_in, const int* in_sizes, int n_in,
                              void* d_out, int out_size, void* d_ws, size_t ws_size,
                              hipStream_t stream) {
  const float* x = (const float*)d_in[0];
  const float* probs = (const float*)d_in[1];
  float* out = (float*)d_out;

  uint8_t* dec = (uint8_t*)d_ws;                       // 16*8190 = 131040 B
  int* idxbuf = (int*)((char*)d_ws + (131072));        // 16*8192*4 = 512 KiB

  dim3 g1((NSTEP + 255) / 256, NB);
  k_decide<<<g1, 256, 0, stream>>>(probs, dec);

  k_scan<<<NB, 256, 0, stream>>>(dec, idxbuf);

  dim3 g3(T_LEN / (256 * 4), NCH, NB);
  k_gather<<<g3, 256, 0, stream>>>(x, idxbuf, out);
}

// Round 4
// 67.822 us; speedup vs baseline: 1.0802x; 1.0802x over previous
//
#include <hip/hip_runtime.h>
#include <stdint.h>

#define T_LEN 8192
#define NSTEP 8190   // T - 2 interior samples
#define NB 16
#define NCH 256
#define CB 4         // channels per gather block

// ---------------- threefry2x32 (exact JAX cipher) ----------------
__device__ __forceinline__ uint32_t rotl32(uint32_t v, int r) {
  return (v << r) | (v >> (32 - r));
}

__device__ __forceinline__ void tf2x32(uint32_t k0, uint32_t k1, uint32_t x0, uint32_t x1,
                                       uint32_t& o0, uint32_t& o1) {
  uint32_t ks2 = k0 ^ k1 ^ 0x1BD11BDAu;
  x0 += k0; x1 += k1;
#define RR(r) { x0 += x1; x1 = rotl32(x1, (r)); x1 ^= x0; }
  RR(13) RR(15) RR(26) RR(6)   x0 += k1;  x1 += ks2 + 1u;
  RR(17) RR(29) RR(16) RR(24)  x0 += ks2; x1 += k0 + 2u;
  RR(13) RR(15) RR(26) RR(6)   x0 += k0;  x1 += k1 + 3u;
  RR(17) RR(29) RR(16) RR(24)  x0 += k1;  x1 += ks2 + 4u;
  RR(13) RR(15) RR(26) RR(6)   x0 += ks2; x1 += k0 + 5u;
#undef RR
  o0 = x0; o1 = x1;
}

// ---------------- K1: per-step categorical decisions (VERIFIED r3) ----------
// PARTITIONABLE threefry semantics (JAX >= 0.4.36 default):
//   split(key, n)[i]          = full cipher pair threefry2x32(key, (hi32(i), lo32(i)))
//   random_bits(key,32,(m,))  = bits1 ^ bits2 of cipher(key, (0, c)), c = 0..m-1
// Record BOTH possible decisions: n (normal row), sp (special row (2,1)),
// packed as byte n | (sp<<2).
__global__ __launch_bounds__(256) void k_decide(const float* __restrict__ probs,
                                                uint8_t* __restrict__ dec) {
  int j = blockIdx.x * 256 + threadIdx.x;
  int b = blockIdx.y;
  if (j >= NSTEP) return;

  uint32_t kb0, kb1;
  tf2x32(0u, 42u, 0u, (uint32_t)b, kb0, kb1);      // split(key(42),16)[b]
  uint32_t s0, s1;
  tf2x32(kb0, kb1, 0u, (uint32_t)j, s0, s1);       // split(kb,8190)[j]

  uint32_t bits[3];
  {
    uint32_t y0, y1;
    tf2x32(s0, s1, 0u, 0u, y0, y1); bits[0] = y0 ^ y1;
    tf2x32(s0, s1, 0u, 1u, y0, y1); bits[1] = y0 ^ y1;
    tf2x32(s0, s1, 0u, 2u, y0, y1); bits[2] = y0 ^ y1;
  }

  double g[3];
#pragma unroll
  for (int c = 0; c < 3; ++c) {
    uint32_t k = bits[c] >> 9;                            // 23-bit mantissa sample
    float u = k ? (float)k * 0x1p-23f : 1.17549435e-38f;  // exact JAX uniform value
    g[c] = -log(-log((double)u));
  }

  double lp = log((double)probs[0]);
  double ls = log((double)probs[1]);
  double l1 = log((double)probs[2 * 9 + 1 * 3 + 1]);
  double l2 = log((double)probs[2 * 9 + 1 * 3 + 2]);

  double v0 = lp + g[0], v1 = ls + g[1], v2 = lp + g[2];
  int n = 0; double best = v0;
  if (v1 > best) { n = 1; best = v1; }
  if (v2 > best) { n = 2; }
  int sp = (l1 + g[1] >= l2 + g[2]) ? 1 : 2;

  dec[b * NSTEP + j] = (uint8_t)(n | (sp << 2));
}

// ---------------- K2: parallel Markov scan -> delta bytes ----------------
// State u = p2*3 + p1 in [0,9). Step: j = (u==7) ? spec : norm; u' = (u%3)*3 + j.
// Output: dbuf[b][t] = j in {0,1,2}; gather source = t + j - 1.
__device__ __forceinline__ uint64_t compose_map(uint64_t f, uint64_t g) {
  uint64_t r = 0;
#pragma unroll
  for (int st = 0; st < 9; ++st) {
    uint32_t fs = (uint32_t)((f >> (4 * st)) & 15u);
    uint32_t gs = (uint32_t)((g >> (4 * fs)) & 15u);
    r |= ((uint64_t)gs) << (4 * st);
  }
  return r;
}

__device__ __forceinline__ uint64_t shflup64(uint64_t v, int delta) {
  int lo = __shfl_up((int)(uint32_t)v, delta, 64);
  int hi = __shfl_up((int)(uint32_t)(v >> 32), delta, 64);
  return (((uint64_t)(uint32_t)hi) << 32) | (uint32_t)lo;
}

#define IDENT_MAP 0x876543210ull

__global__ __launch_bounds__(256) void k_scan(const uint8_t* __restrict__ dec,
                                              uint8_t* __restrict__ dbuf) {
  int b = blockIdx.x;
  int tid = threadIdx.x;
  int lane = tid & 63, wave = tid >> 6;
  int begin = tid * 32;
  const uint8_t* row = dec + b * NSTEP;

  // phase 1: build this chunk's 9-state map
  uint64_t M = IDENT_MAP;
#pragma unroll
  for (int t = 0; t < 32; ++t) {
    int step = begin + t;
    if (step < NSTEP) {
      int d = row[step];
      uint32_t n = d & 3u, s = (d >> 2) & 3u;
      uint64_t Mn = 0;
#pragma unroll
      for (int st = 0; st < 9; ++st) {
        uint32_t u = (uint32_t)((M >> (4 * st)) & 15u);
        uint32_t div3 = (u * 11u) >> 5;          // u/3 for u<9
        uint32_t p1 = u - 3u * div3;
        uint32_t jj = (u == 7u) ? s : n;
        Mn |= ((uint64_t)(p1 * 3u + jj)) << (4 * st);
      }
      M = Mn;
    }
  }

  // phase 2a: wave-inclusive scan
  uint64_t I = M;
#pragma unroll
  for (int off = 1; off < 64; off <<= 1) {
    uint64_t Mp = shflup64(I, off);
    uint64_t c = compose_map(Mp, I);
    I = (lane >= off) ? c : I;
  }

  __shared__ uint64_t wmap[4];
  if (lane == 63) wmap[wave] = I;
  __syncthreads();

  // phase 2b: exclusive prefix
  uint64_t W = IDENT_MAP;
  for (int w = 0; w < wave; ++w) W = compose_map(W, wmap[w]);
  uint64_t E = shflup64(I, 1);
  if (lane == 0) E = IDENT_MAP;
  uint64_t X = compose_map(W, E);

  int state = (int)((X >> (4 * 4)) & 15u);  // applied to initial chain state (1,1)=4

  // phase 3: replay chunk, emit delta bytes dbuf[b][step+1] = j
  uint8_t* orow = dbuf + b * T_LEN;
#pragma unroll
  for (int t = 0; t < 32; ++t) {
    int step = begin + t;
    if (step < NSTEP) {
      int d = row[step];
      uint32_t n = d & 3u, s = (d >> 2) & 3u;
      uint32_t jj = (state == 7) ? s : n;
      uint32_t div3 = ((uint32_t)state * 11u) >> 5;
      uint32_t p1 = (uint32_t)state - 3u * div3;
      state = (int)(p1 * 3u + jj);
      orow[step + 1] = (uint8_t)jj;
    }
  }
  if (tid == 0) { orow[0] = 1; orow[T_LEN - 1] = 1; }   // forced j=1 -> src=t
}

// ---------------- K3: shift-select gather ----------------
// out[b,i,t] = x[b,i,t+d-1], d in {0,1,2}. Each thread covers 4 t, needs
// x[t0-1..t0+4]: one aligned float4 + halo via shuffles (edge lanes load 1 elem).
// CB channels per block share one uchar4 delta load.
__global__ __launch_bounds__(256) void k_gather(const float* __restrict__ x,
                                                const uint8_t* __restrict__ dbuf,
                                                float* __restrict__ out) {
  int b = blockIdx.z;
  int i0 = blockIdx.y * CB;
  int tid = threadIdx.x;
  int lane = tid & 63;
  int t0 = (blockIdx.x * 256 + tid) * 4;

  const uchar4 du = *(const uchar4*)(dbuf + b * T_LEN + t0);
  const int d0 = du.x, d1 = du.y, d2 = du.z, d3 = du.w;

#pragma unroll
  for (int c = 0; c < CB; ++c) {
    const float* __restrict__ xr = x + ((size_t)(b * NCH + i0 + c)) * T_LEN;
    float4 v = *(const float4*)(xr + t0);
    float left  = __shfl_up(v.w, 1);    // lane l-1's v.w = x[t0-1]
    float right = __shfl_down(v.x, 1);  // lane l+1's v.x = x[t0+4]
    if (lane == 0)  left  = (t0 > 0) ? xr[t0 - 1] : 0.0f;
    if (lane == 63) right = (t0 + 4 < T_LEN) ? xr[t0 + 4] : 0.0f;

    float4 o;
    o.x = (d0 == 0) ? left : ((d0 == 1) ? v.x : v.y);
    o.y = (d1 == 0) ? v.x  : ((d1 == 1) ? v.y : v.z);
    o.z = (d2 == 0) ? v.y  : ((d2 == 1) ? v.z : v.w);
    o.w = (d3 == 0) ? v.z  : ((d3 == 1) ? v.w : right);
    *(float4*)(out + ((size_t)(b * NCH + i0 + c)) * T_LEN + t0) = o;
  }
}

extern "C" void kernel_launch(void* const* d_in, const int* in_sizes, int n_in,
                              void* d_out, int out_size, void* d_ws, size_t ws_size,
                              hipStream_t stream) {
  const float* x = (const float*)d_in[0];
  const float* probs = (const float*)d_in[1];
  float* out = (float*)d_out;

  uint8_t* dec = (uint8_t*)d_ws;                       // 16*8190 = 131040 B
  uint8_t* dbuf = (uint8_t*)d_ws + 131072;             // 16*8192 = 128 KiB

  dim3 g1((NSTEP + 255) / 256, NB);
  k_decide<<<g1, 256, 0, stream>>>(probs, dec);

  k_scan<<<NB, 256, 0, stream>>>(dec, dbuf);

  dim3 g3(T_LEN / (256 * 4), NCH / CB, NB);
  k_gather<<<g3, 256, 0, stream>>>(x, dbuf, out);
}

// Round 5
// 67.445 us; speedup vs baseline: 1.0863x; 1.0056x over previous
//
#include <hip/hip_runtime.h>
#include <stdint.h>

#define T_LEN 8192
#define NSTEP 8190   // T - 2 interior samples
#define NB 16
#define NCH 256
#define CB 4         // channels per gather block

// ---------------- threefry2x32 (exact JAX cipher) ----------------
__device__ __forceinline__ uint32_t rotl32(uint32_t v, int r) {
  return (v << r) | (v >> (32 - r));
}

__device__ __forceinline__ void tf2x32(uint32_t k0, uint32_t k1, uint32_t x0, uint32_t x1,
                                       uint32_t& o0, uint32_t& o1) {
  uint32_t ks2 = k0 ^ k1 ^ 0x1BD11BDAu;
  x0 += k0; x1 += k1;
#define RR(r) { x0 += x1; x1 = rotl32(x1, (r)); x1 ^= x0; }
  RR(13) RR(15) RR(26) RR(6)   x0 += k1;  x1 += ks2 + 1u;
  RR(17) RR(29) RR(16) RR(24)  x0 += ks2; x1 += k0 + 2u;
  RR(13) RR(15) RR(26) RR(6)   x0 += k0;  x1 += k1 + 3u;
  RR(17) RR(29) RR(16) RR(24)  x0 += k1;  x1 += ks2 + 4u;
  RR(13) RR(15) RR(26) RR(6)   x0 += ks2; x1 += k0 + 5u;
#undef RR
  o0 = x0; o1 = x1;
}

// ---------------- K1: per-step categorical decisions (VERIFIED r3) ----------
// PARTITIONABLE threefry semantics (JAX >= 0.4.36 default):
//   split(key, n)[i]          = full cipher pair threefry2x32(key, (hi32(i), lo32(i)))
//   random_bits(key,32,(m,))  = bits1 ^ bits2 of cipher(key, (0, c)), c = 0..m-1
// Record BOTH possible decisions: n (normal row), sp (special row (2,1)),
// packed as byte n | (sp<<2).
__global__ __launch_bounds__(256) void k_decide(const float* __restrict__ probs,
                                                uint8_t* __restrict__ dec) {
  int j = blockIdx.x * 256 + threadIdx.x;
  int b = blockIdx.y;
  if (j >= NSTEP) return;

  uint32_t kb0, kb1;
  tf2x32(0u, 42u, 0u, (uint32_t)b, kb0, kb1);      // split(key(42),16)[b]
  uint32_t s0, s1;
  tf2x32(kb0, kb1, 0u, (uint32_t)j, s0, s1);       // split(kb,8190)[j]

  uint32_t bits[3];
  {
    uint32_t y0, y1;
    tf2x32(s0, s1, 0u, 0u, y0, y1); bits[0] = y0 ^ y1;
    tf2x32(s0, s1, 0u, 1u, y0, y1); bits[1] = y0 ^ y1;
    tf2x32(s0, s1, 0u, 2u, y0, y1); bits[2] = y0 ^ y1;
  }

  double g[3];
#pragma unroll
  for (int c = 0; c < 3; ++c) {
    uint32_t k = bits[c] >> 9;                            // 23-bit mantissa sample
    float u = k ? (float)k * 0x1p-23f : 1.17549435e-38f;  // exact JAX uniform value
    g[c] = -log(-log((double)u));
  }

  double lp = log((double)probs[0]);
  double ls = log((double)probs[1]);
  double l1 = log((double)probs[2 * 9 + 1 * 3 + 1]);
  double l2 = log((double)probs[2 * 9 + 1 * 3 + 2]);

  double v0 = lp + g[0], v1 = ls + g[1], v2 = lp + g[2];
  int n = 0; double best = v0;
  if (v1 > best) { n = 1; best = v1; }
  if (v2 > best) { n = 2; }
  int sp = (l1 + g[1] >= l2 + g[2]) ? 1 : 2;

  dec[b * NSTEP + j] = (uint8_t)(n | (sp << 2));
}

// ---------------- K2: parallel Markov scan -> delta bytes (VERIFIED r4) ----
// State u = p2*3 + p1 in [0,9). Step: j = (u==7) ? spec : norm; u' = (u%3)*3 + j.
// Output: dbuf[b][t] = j in {0,1,2}; gather source = t + j - 1.
__device__ __forceinline__ uint64_t compose_map(uint64_t f, uint64_t g) {
  uint64_t r = 0;
#pragma unroll
  for (int st = 0; st < 9; ++st) {
    uint32_t fs = (uint32_t)((f >> (4 * st)) & 15u);
    uint32_t gs = (uint32_t)((g >> (4 * fs)) & 15u);
    r |= ((uint64_t)gs) << (4 * st);
  }
  return r;
}

__device__ __forceinline__ uint64_t shflup64(uint64_t v, int delta) {
  int lo = __shfl_up((int)(uint32_t)v, delta, 64);
  int hi = __shfl_up((int)(uint32_t)(v >> 32), delta, 64);
  return (((uint64_t)(uint32_t)hi) << 32) | (uint32_t)lo;
}

#define IDENT_MAP 0x876543210ull

__global__ __launch_bounds__(256) void k_scan(const uint8_t* __restrict__ dec,
                                              uint8_t* __restrict__ dbuf) {
  int b = blockIdx.x;
  int tid = threadIdx.x;
  int lane = tid & 63, wave = tid >> 6;
  int begin = tid * 32;
  const uint8_t* row = dec + b * NSTEP;

  // phase 1: build this chunk's 9-state map
  uint64_t M = IDENT_MAP;
#pragma unroll
  for (int t = 0; t < 32; ++t) {
    int step = begin + t;
    if (step < NSTEP) {
      int d = row[step];
      uint32_t n = d & 3u, s = (d >> 2) & 3u;
      uint64_t Mn = 0;
#pragma unroll
      for (int st = 0; st < 9; ++st) {
        uint32_t u = (uint32_t)((M >> (4 * st)) & 15u);
        uint32_t div3 = (u * 11u) >> 5;          // u/3 for u<9
        uint32_t p1 = u - 3u * div3;
        uint32_t jj = (u == 7u) ? s : n;
        Mn |= ((uint64_t)(p1 * 3u + jj)) << (4 * st);
      }
      M = Mn;
    }
  }

  // phase 2a: wave-inclusive scan
  uint64_t I = M;
#pragma unroll
  for (int off = 1; off < 64; off <<= 1) {
    uint64_t Mp = shflup64(I, off);
    uint64_t c = compose_map(Mp, I);
    I = (lane >= off) ? c : I;
  }

  __shared__ uint64_t wmap[4];
  if (lane == 63) wmap[wave] = I;
  __syncthreads();

  // phase 2b: exclusive prefix
  uint64_t W = IDENT_MAP;
  for (int w = 0; w < wave; ++w) W = compose_map(W, wmap[w]);
  uint64_t E = shflup64(I, 1);
  if (lane == 0) E = IDENT_MAP;
  uint64_t X = compose_map(W, E);

  int state = (int)((X >> (4 * 4)) & 15u);  // applied to initial chain state (1,1)=4

  // phase 3: replay chunk, emit delta bytes dbuf[b][step+1] = j
  uint8_t* orow = dbuf + b * T_LEN;
#pragma unroll
  for (int t = 0; t < 32; ++t) {
    int step = begin + t;
    if (step < NSTEP) {
      int d = row[step];
      uint32_t n = d & 3u, s = (d >> 2) & 3u;
      uint32_t jj = (state == 7) ? s : n;
      uint32_t div3 = ((uint32_t)state * 11u) >> 5;
      uint32_t p1 = (uint32_t)state - 3u * div3;
      state = (int)(p1 * 3u + jj);
      orow[step + 1] = (uint8_t)jj;
    }
  }
  if (tid == 0) { orow[0] = 1; orow[T_LEN - 1] = 1; }   // forced j=1 -> src=t
}

// ---------------- K3: shift-select gather (branch-free, shuffle-free) ------
// out[b,i,t] = x[b,i,t+d-1], d in {0,1,2}. Per thread: 4 t-positions × CB
// channels. Halo x[t0-1], x[t0+4] come from plain coalesced scalar loads
// (L1-resident lines), clamped at the edges — the forced d=1 at t=0 and
// t=T-1 guarantees clamped values are never selected. All 12 loads issued
// before any select -> ~12 outstanding loads/wave, no divergence, no shfl.
__global__ __launch_bounds__(256) void k_gather(const float* __restrict__ x,
                                                const uint8_t* __restrict__ dbuf,
                                                float* __restrict__ out) {
  const int b = blockIdx.z;
  const int i0 = blockIdx.y * CB;
  const int t0 = (blockIdx.x * 256 + threadIdx.x) * 4;

  const uchar4 du = *(const uchar4*)(dbuf + b * T_LEN + t0);
  const int tl = (t0 == 0) ? 0 : t0 - 1;                    // clamp (never selected)
  const int tr = (t0 + 4 >= T_LEN) ? (T_LEN - 1) : t0 + 4;  // clamp (never selected)

  const float* __restrict__ xb = x + ((size_t)(b * NCH + i0)) * T_LEN;

  float4 v[CB];
  float L[CB], R[CB];
#pragma unroll
  for (int c = 0; c < CB; ++c) {
    const float* __restrict__ xr = xb + (size_t)c * T_LEN;
    v[c] = *(const float4*)(xr + t0);
    L[c] = xr[tl];
    R[c] = xr[tr];
  }

  float* __restrict__ ob = out + ((size_t)(b * NCH + i0)) * T_LEN + t0;
#pragma unroll
  for (int c = 0; c < CB; ++c) {
    float4 o;
    o.x = (du.x == 0) ? L[c]    : ((du.x == 1) ? v[c].x : v[c].y);
    o.y = (du.y == 0) ? v[c].x  : ((du.y == 1) ? v[c].y : v[c].z);
    o.z = (du.z == 0) ? v[c].y  : ((du.z == 1) ? v[c].z : v[c].w);
    o.w = (du.w == 0) ? v[c].z  : ((du.w == 1) ? v[c].w : R[c]);
    *(float4*)(ob + (size_t)c * T_LEN) = o;
  }
}

extern "C" void kernel_launch(void* const* d_in, const int* in_sizes, int n_in,
                              void* d_out, int out_size, void* d_ws, size_t ws_size,
                              hipStream_t stream) {
  const float* x = (const float*)d_in[0];
  const float* probs = (const float*)d_in[1];
  float* out = (float*)d_out;

  uint8_t* dec = (uint8_t*)d_ws;                       // 16*8190 = 131040 B
  uint8_t* dbuf = (uint8_t*)d_ws + 131072;             // 16*8192 = 128 KiB

  dim3 g1((NSTEP + 255) / 256, NB);
  k_decide<<<g1, 256, 0, stream>>>(probs, dec);

  k_scan<<<NB, 256, 0, stream>>>(dec, dbuf);

  dim3 g3(T_LEN / (256 * 4), NCH / CB, NB);
  k_gather<<<g3, 256, 0, stream>>>(x, dbuf, out);
}

// Round 6
// 65.933 us; speedup vs baseline: 1.1112x; 1.0229x over previous
//
#include <hip/hip_runtime.h>
#include <stdint.h>

#define T_LEN 8192
#define NSTEP 8190   // T - 2 interior samples
#define NB 16
#define NCH 256
#define CB 4         // channels per gather block

// ---------------- threefry2x32 (exact JAX cipher) ----------------
__device__ __forceinline__ uint32_t rotl32(uint32_t v, int r) {
  return (v << r) | (v >> (32 - r));
}

__device__ __forceinline__ void tf2x32(uint32_t k0, uint32_t k1, uint32_t x0, uint32_t x1,
                                       uint32_t& o0, uint32_t& o1) {
  uint32_t ks2 = k0 ^ k1 ^ 0x1BD11BDAu;
  x0 += k0; x1 += k1;
#define RR(r) { x0 += x1; x1 = rotl32(x1, (r)); x1 ^= x0; }
  RR(13) RR(15) RR(26) RR(6)   x0 += k1;  x1 += ks2 + 1u;
  RR(17) RR(29) RR(16) RR(24)  x0 += ks2; x1 += k0 + 2u;
  RR(13) RR(15) RR(26) RR(6)   x0 += k0;  x1 += k1 + 3u;
  RR(17) RR(29) RR(16) RR(24)  x0 += k1;  x1 += ks2 + 4u;
  RR(13) RR(15) RR(26) RR(6)   x0 += ks2; x1 += k0 + 5u;
#undef RR
  o0 = x0; o1 = x1;
}

// ---------------- K1: per-step categorical decisions (VERIFIED r3) ----------
// PARTITIONABLE threefry semantics (JAX >= 0.4.36 default):
//   split(key, n)[i]          = full cipher pair threefry2x32(key, (hi32(i), lo32(i)))
//   random_bits(key,32,(m,))  = bits1 ^ bits2 of cipher(key, (0, c)), c = 0..m-1
// Record BOTH possible decisions: n (normal row), sp (special row (2,1)),
// packed as byte n | (sp<<2).
__global__ __launch_bounds__(256) void k_decide(const float* __restrict__ probs,
                                                uint8_t* __restrict__ dec) {
  int j = blockIdx.x * 256 + threadIdx.x;
  int b = blockIdx.y;
  if (j >= NSTEP) return;

  uint32_t kb0, kb1;
  tf2x32(0u, 42u, 0u, (uint32_t)b, kb0, kb1);      // split(key(42),16)[b]
  uint32_t s0, s1;
  tf2x32(kb0, kb1, 0u, (uint32_t)j, s0, s1);       // split(kb,8190)[j]

  uint32_t bits[3];
  {
    uint32_t y0, y1;
    tf2x32(s0, s1, 0u, 0u, y0, y1); bits[0] = y0 ^ y1;
    tf2x32(s0, s1, 0u, 1u, y0, y1); bits[1] = y0 ^ y1;
    tf2x32(s0, s1, 0u, 2u, y0, y1); bits[2] = y0 ^ y1;
  }

  double g[3];
#pragma unroll
  for (int c = 0; c < 3; ++c) {
    uint32_t k = bits[c] >> 9;                            // 23-bit mantissa sample
    float u = k ? (float)k * 0x1p-23f : 1.17549435e-38f;  // exact JAX uniform value
    g[c] = -log(-log((double)u));
  }

  double lp = log((double)probs[0]);
  double ls = log((double)probs[1]);
  double l1 = log((double)probs[2 * 9 + 1 * 3 + 1]);
  double l2 = log((double)probs[2 * 9 + 1 * 3 + 2]);

  double v0 = lp + g[0], v1 = ls + g[1], v2 = lp + g[2];
  int n = 0; double best = v0;
  if (v1 > best) { n = 1; best = v1; }
  if (v2 > best) { n = 2; }
  int sp = (l1 + g[1] >= l2 + g[2]) ? 1 : 2;

  dec[b * NSTEP + j] = (uint8_t)(n | (sp << 2));
}

// ---------------- K2: parallel Markov scan -> delta bytes (VERIFIED r4) ----
// State u = p2*3 + p1 in [0,9). Step: j = (u==7) ? spec : norm; u' = (u%3)*3 + j.
// Output: dbuf[b][t] = j in {0,1,2}; gather source = t + j - 1.
__device__ __forceinline__ uint64_t compose_map(uint64_t f, uint64_t g) {
  uint64_t r = 0;
#pragma unroll
  for (int st = 0; st < 9; ++st) {
    uint32_t fs = (uint32_t)((f >> (4 * st)) & 15u);
    uint32_t gs = (uint32_t)((g >> (4 * fs)) & 15u);
    r |= ((uint64_t)gs) << (4 * st);
  }
  return r;
}

__device__ __forceinline__ uint64_t shflup64(uint64_t v, int delta) {
  int lo = __shfl_up((int)(uint32_t)v, delta, 64);
  int hi = __shfl_up((int)(uint32_t)(v >> 32), delta, 64);
  return (((uint64_t)(uint32_t)hi) << 32) | (uint32_t)lo;
}

#define IDENT_MAP 0x876543210ull

__global__ __launch_bounds__(256) void k_scan(const uint8_t* __restrict__ dec,
                                              uint8_t* __restrict__ dbuf) {
  int b = blockIdx.x;
  int tid = threadIdx.x;
  int lane = tid & 63, wave = tid >> 6;
  int begin = tid * 32;
  const uint8_t* row = dec + b * NSTEP;

  // phase 1: build this chunk's 9-state map
  uint64_t M = IDENT_MAP;
#pragma unroll
  for (int t = 0; t < 32; ++t) {
    int step = begin + t;
    if (step < NSTEP) {
      int d = row[step];
      uint32_t n = d & 3u, s = (d >> 2) & 3u;
      uint64_t Mn = 0;
#pragma unroll
      for (int st = 0; st < 9; ++st) {
        uint32_t u = (uint32_t)((M >> (4 * st)) & 15u);
        uint32_t div3 = (u * 11u) >> 5;          // u/3 for u<9
        uint32_t p1 = u - 3u * div3;
        uint32_t jj = (u == 7u) ? s : n;
        Mn |= ((uint64_t)(p1 * 3u + jj)) << (4 * st);
      }
      M = Mn;
    }
  }

  // phase 2a: wave-inclusive scan
  uint64_t I = M;
#pragma unroll
  for (int off = 1; off < 64; off <<= 1) {
    uint64_t Mp = shflup64(I, off);
    uint64_t c = compose_map(Mp, I);
    I = (lane >= off) ? c : I;
  }

  __shared__ uint64_t wmap[4];
  if (lane == 63) wmap[wave] = I;
  __syncthreads();

  // phase 2b: exclusive prefix
  uint64_t W = IDENT_MAP;
  for (int w = 0; w < wave; ++w) W = compose_map(W, wmap[w]);
  uint64_t E = shflup64(I, 1);
  if (lane == 0) E = IDENT_MAP;
  uint64_t X = compose_map(W, E);

  int state = (int)((X >> (4 * 4)) & 15u);  // applied to initial chain state (1,1)=4

  // phase 3: replay chunk, emit delta bytes dbuf[b][step+1] = j
  uint8_t* orow = dbuf + b * T_LEN;
#pragma unroll
  for (int t = 0; t < 32; ++t) {
    int step = begin + t;
    if (step < NSTEP) {
      int d = row[step];
      uint32_t n = d & 3u, s = (d >> 2) & 3u;
      uint32_t jj = (state == 7) ? s : n;
      uint32_t div3 = ((uint32_t)state * 11u) >> 5;
      uint32_t p1 = (uint32_t)state - 3u * div3;
      state = (int)(p1 * 3u + jj);
      orow[step + 1] = (uint8_t)jj;
    }
  }
  if (tid == 0) { orow[0] = 1; orow[T_LEN - 1] = 1; }   // forced j=1 -> src=t
}

// ---------------- K3: shift-select gather (nontemporal stores) -------------
// out[b,i,t] = x[b,i,t+d-1], d in {0,1,2}. Identical to r5 EXCEPT the output
// stores are non-temporal: out (128 MiB) no longer allocates in L3, so x
// (128 MiB) stays Infinity-Cache-resident across graph replays instead of
// being thrashed by the write stream. Single-variable change.
typedef float f32x4 __attribute__((ext_vector_type(4)));

__global__ __launch_bounds__(256) void k_gather(const float* __restrict__ x,
                                                const uint8_t* __restrict__ dbuf,
                                                float* __restrict__ out) {
  const int b = blockIdx.z;
  const int i0 = blockIdx.y * CB;
  const int t0 = (blockIdx.x * 256 + threadIdx.x) * 4;

  const uchar4 du = *(const uchar4*)(dbuf + b * T_LEN + t0);
  const int tl = (t0 == 0) ? 0 : t0 - 1;                    // clamp (never selected)
  const int tr = (t0 + 4 >= T_LEN) ? (T_LEN - 1) : t0 + 4;  // clamp (never selected)

  const float* __restrict__ xb = x + ((size_t)(b * NCH + i0)) * T_LEN;

  float4 v[CB];
  float L[CB], R[CB];
#pragma unroll
  for (int c = 0; c < CB; ++c) {
    const float* __restrict__ xr = xb + (size_t)c * T_LEN;
    v[c] = *(const float4*)(xr + t0);
    L[c] = xr[tl];
    R[c] = xr[tr];
  }

  float* __restrict__ ob = out + ((size_t)(b * NCH + i0)) * T_LEN + t0;
#pragma unroll
  for (int c = 0; c < CB; ++c) {
    f32x4 o;
    o.x = (du.x == 0) ? L[c]    : ((du.x == 1) ? v[c].x : v[c].y);
    o.y = (du.y == 0) ? v[c].x  : ((du.y == 1) ? v[c].y : v[c].z);
    o.z = (du.z == 0) ? v[c].y  : ((du.z == 1) ? v[c].z : v[c].w);
    o.w = (du.w == 0) ? v[c].z  : ((du.w == 1) ? v[c].w : R[c]);
    __builtin_nontemporal_store(o, (f32x4*)(ob + (size_t)c * T_LEN));
  }
}

extern "C" void kernel_launch(void* const* d_in, const int* in_sizes, int n_in,
                              void* d_out, int out_size, void* d_ws, size_t ws_size,
                              hipStream_t stream) {
  const float* x = (const float*)d_in[0];
  const float* probs = (const float*)d_in[1];
  float* out = (float*)d_out;

  uint8_t* dec = (uint8_t*)d_ws;                       // 16*8190 = 131040 B
  uint8_t* dbuf = (uint8_t*)d_ws + 131072;             // 16*8192 = 128 KiB

  dim3 g1((NSTEP + 255) / 256, NB);
  k_decide<<<g1, 256, 0, stream>>>(probs, dec);

  k_scan<<<NB, 256, 0, stream>>>(dec, dbuf);

  dim3 g3(T_LEN / (256 * 4), NCH / CB, NB);
  k_gather<<<g3, 256, 0, stream>>>(x, dbuf, out);
}

// Round 7
// 65.530 us; speedup vs baseline: 1.1180x; 1.0061x over previous
//
#include <hip/hip_runtime.h>
#include <stdint.h>

#define T_LEN 8192
#define NSTEP 8190   // T - 2 interior samples
#define NB 16
#define NCH 256
#define CB 4         // channels per gather block

// ---------------- threefry2x32 (exact JAX cipher) ----------------
__device__ __forceinline__ uint32_t rotl32(uint32_t v, int r) {
  return (v << r) | (v >> (32 - r));
}

__device__ __forceinline__ void tf2x32(uint32_t k0, uint32_t k1, uint32_t x0, uint32_t x1,
                                       uint32_t& o0, uint32_t& o1) {
  uint32_t ks2 = k0 ^ k1 ^ 0x1BD11BDAu;
  x0 += k0; x1 += k1;
#define RR(r) { x0 += x1; x1 = rotl32(x1, (r)); x1 ^= x0; }
  RR(13) RR(15) RR(26) RR(6)   x0 += k1;  x1 += ks2 + 1u;
  RR(17) RR(29) RR(16) RR(24)  x0 += ks2; x1 += k0 + 2u;
  RR(13) RR(15) RR(26) RR(6)   x0 += k0;  x1 += k1 + 3u;
  RR(17) RR(29) RR(16) RR(24)  x0 += k1;  x1 += ks2 + 4u;
  RR(13) RR(15) RR(26) RR(6)   x0 += ks2; x1 += k0 + 5u;
#undef RR
  o0 = x0; o1 = x1;
}

// ---------------- K1: per-step categorical decisions (VERIFIED r3) ----------
// PARTITIONABLE threefry semantics (JAX >= 0.4.36 default):
//   split(key, n)[i]          = full cipher pair threefry2x32(key, (hi32(i), lo32(i)))
//   random_bits(key,32,(m,))  = bits1 ^ bits2 of cipher(key, (0, c)), c = 0..m-1
// Record BOTH possible decisions: n (normal row), sp (special row (2,1)),
// packed as byte n | (sp<<2).
__global__ __launch_bounds__(256) void k_decide(const float* __restrict__ probs,
                                                uint8_t* __restrict__ dec) {
  int j = blockIdx.x * 256 + threadIdx.x;
  int b = blockIdx.y;
  if (j >= NSTEP) return;

  uint32_t kb0, kb1;
  tf2x32(0u, 42u, 0u, (uint32_t)b, kb0, kb1);      // split(key(42),16)[b]
  uint32_t s0, s1;
  tf2x32(kb0, kb1, 0u, (uint32_t)j, s0, s1);       // split(kb,8190)[j]

  uint32_t bits[3];
  {
    uint32_t y0, y1;
    tf2x32(s0, s1, 0u, 0u, y0, y1); bits[0] = y0 ^ y1;
    tf2x32(s0, s1, 0u, 1u, y0, y1); bits[1] = y0 ^ y1;
    tf2x32(s0, s1, 0u, 2u, y0, y1); bits[2] = y0 ^ y1;
  }

  double g[3];
#pragma unroll
  for (int c = 0; c < 3; ++c) {
    uint32_t k = bits[c] >> 9;                            // 23-bit mantissa sample
    float u = k ? (float)k * 0x1p-23f : 1.17549435e-38f;  // exact JAX uniform value
    g[c] = -log(-log((double)u));
  }

  double lp = log((double)probs[0]);
  double ls = log((double)probs[1]);
  double l1 = log((double)probs[2 * 9 + 1 * 3 + 1]);
  double l2 = log((double)probs[2 * 9 + 1 * 3 + 2]);

  double v0 = lp + g[0], v1 = ls + g[1], v2 = lp + g[2];
  int n = 0; double best = v0;
  if (v1 > best) { n = 1; best = v1; }
  if (v2 > best) { n = 2; }
  int sp = (l1 + g[1] >= l2 + g[2]) ? 1 : 2;

  dec[b * NSTEP + j] = (uint8_t)(n | (sp << 2));
}

// ---------------- K2: parallel Markov scan -> delta bytes (VERIFIED r4) ----
// State u = p2*3 + p1 in [0,9). Step: j = (u==7) ? spec : norm; u' = (u%3)*3 + j.
// Output: dbuf[b][t] = j in {0,1,2}; gather source = t + j - 1.
__device__ __forceinline__ uint64_t compose_map(uint64_t f, uint64_t g) {
  uint64_t r = 0;
#pragma unroll
  for (int st = 0; st < 9; ++st) {
    uint32_t fs = (uint32_t)((f >> (4 * st)) & 15u);
    uint32_t gs = (uint32_t)((g >> (4 * fs)) & 15u);
    r |= ((uint64_t)gs) << (4 * st);
  }
  return r;
}

__device__ __forceinline__ uint64_t shflup64(uint64_t v, int delta) {
  int lo = __shfl_up((int)(uint32_t)v, delta, 64);
  int hi = __shfl_up((int)(uint32_t)(v >> 32), delta, 64);
  return (((uint64_t)(uint32_t)hi) << 32) | (uint32_t)lo;
}

#define IDENT_MAP 0x876543210ull

__global__ __launch_bounds__(256) void k_scan(const uint8_t* __restrict__ dec,
                                              uint8_t* __restrict__ dbuf) {
  int b = blockIdx.x;
  int tid = threadIdx.x;
  int lane = tid & 63, wave = tid >> 6;
  int begin = tid * 32;
  const uint8_t* row = dec + b * NSTEP;

  // phase 1: build this chunk's 9-state map
  uint64_t M = IDENT_MAP;
#pragma unroll
  for (int t = 0; t < 32; ++t) {
    int step = begin + t;
    if (step < NSTEP) {
      int d = row[step];
      uint32_t n = d & 3u, s = (d >> 2) & 3u;
      uint64_t Mn = 0;
#pragma unroll
      for (int st = 0; st < 9; ++st) {
        uint32_t u = (uint32_t)((M >> (4 * st)) & 15u);
        uint32_t div3 = (u * 11u) >> 5;          // u/3 for u<9
        uint32_t p1 = u - 3u * div3;
        uint32_t jj = (u == 7u) ? s : n;
        Mn |= ((uint64_t)(p1 * 3u + jj)) << (4 * st);
      }
      M = Mn;
    }
  }

  // phase 2a: wave-inclusive scan
  uint64_t I = M;
#pragma unroll
  for (int off = 1; off < 64; off <<= 1) {
    uint64_t Mp = shflup64(I, off);
    uint64_t c = compose_map(Mp, I);
    I = (lane >= off) ? c : I;
  }

  __shared__ uint64_t wmap[4];
  if (lane == 63) wmap[wave] = I;
  __syncthreads();

  // phase 2b: exclusive prefix
  uint64_t W = IDENT_MAP;
  for (int w = 0; w < wave; ++w) W = compose_map(W, wmap[w]);
  uint64_t E = shflup64(I, 1);
  if (lane == 0) E = IDENT_MAP;
  uint64_t X = compose_map(W, E);

  int state = (int)((X >> (4 * 4)) & 15u);  // applied to initial chain state (1,1)=4

  // phase 3: replay chunk, emit delta bytes dbuf[b][step+1] = j
  uint8_t* orow = dbuf + b * T_LEN;
#pragma unroll
  for (int t = 0; t < 32; ++t) {
    int step = begin + t;
    if (step < NSTEP) {
      int d = row[step];
      uint32_t n = d & 3u, s = (d >> 2) & 3u;
      uint32_t jj = (state == 7) ? s : n;
      uint32_t div3 = ((uint32_t)state * 11u) >> 5;
      uint32_t p1 = (uint32_t)state - 3u * div3;
      state = (int)(p1 * 3u + jj);
      orow[step + 1] = (uint8_t)jj;
    }
  }
  if (tid == 0) { orow[0] = 1; orow[T_LEN - 1] = 1; }   // forced j=1 -> src=t
}

// ---------------- K3: shift-select gather (forced-MLP) ---------------------
// out[b,i,t] = x[b,i,t+d-1], d in {0,1,2}. Identical to r6 EXCEPT an asm
// compiler barrier between the load phase and the select/store phase: the
// "memory" clobber pins all 13 VMEM loads (1 dbuf + 4 float4 + 8 halo
// scalars) before any consumer, preventing the compiler from re-fusing the
// loops into 4 serialized per-channel chains (r4-r6 showed VGPR_Count=16 =>
// ~3 outstanding loads => latency-bound at ~2 TB/s read per Little's law).
typedef float f32x4 __attribute__((ext_vector_type(4)));

__global__ __launch_bounds__(256) void k_gather(const float* __restrict__ x,
                                                const uint8_t* __restrict__ dbuf,
                                                float* __restrict__ out) {
  const int b = blockIdx.z;
  const int i0 = blockIdx.y * CB;
  const int t0 = (blockIdx.x * 256 + threadIdx.x) * 4;

  const uchar4 du = *(const uchar4*)(dbuf + b * T_LEN + t0);
  const int tl = (t0 == 0) ? 0 : t0 - 1;                    // clamp (never selected)
  const int tr = (t0 + 4 >= T_LEN) ? (T_LEN - 1) : t0 + 4;  // clamp (never selected)

  const float* __restrict__ xb = x + ((size_t)(b * NCH + i0)) * T_LEN;

  float4 v[CB];
  float L[CB], R[CB];
#pragma unroll
  for (int c = 0; c < CB; ++c) {
    const float* __restrict__ xr = xb + (size_t)c * T_LEN;
    v[c] = *(const float4*)(xr + t0);
    L[c] = xr[tl];
    R[c] = xr[tr];
  }

  // Compiler barrier: all loads above must be issued before anything below.
  asm volatile("" ::: "memory");

  float* __restrict__ ob = out + ((size_t)(b * NCH + i0)) * T_LEN + t0;
#pragma unroll
  for (int c = 0; c < CB; ++c) {
    f32x4 o;
    o.x = (du.x == 0) ? L[c]    : ((du.x == 1) ? v[c].x : v[c].y);
    o.y = (du.y == 0) ? v[c].x  : ((du.y == 1) ? v[c].y : v[c].z);
    o.z = (du.z == 0) ? v[c].y  : ((du.z == 1) ? v[c].z : v[c].w);
    o.w = (du.w == 0) ? v[c].z  : ((du.w == 1) ? v[c].w : R[c]);
    __builtin_nontemporal_store(o, (f32x4*)(ob + (size_t)c * T_LEN));
  }
}

extern "C" void kernel_launch(void* const* d_in, const int* in_sizes, int n_in,
                              void* d_out, int out_size, void* d_ws, size_t ws_size,
                              hipStream_t stream) {
  const float* x = (const float*)d_in[0];
  const float* probs = (const float*)d_in[1];
  float* out = (float*)d_out;

  uint8_t* dec = (uint8_t*)d_ws;                       // 16*8190 = 131040 B
  uint8_t* dbuf = (uint8_t*)d_ws + 131072;             // 16*8192 = 128 KiB

  dim3 g1((NSTEP + 255) / 256, NB);
  k_decide<<<g1, 256, 0, stream>>>(probs, dec);

  k_scan<<<NB, 256, 0, stream>>>(dec, dbuf);

  dim3 g3(T_LEN / (256 * 4), NCH / CB, NB);
  k_gather<<<g3, 256, 0, stream>>>(x, dbuf, out);
}

// Round 8
// 65.311 us; speedup vs baseline: 1.1218x; 1.0033x over previous
//
#include <hip/hip_runtime.h>
#include <stdint.h>

#define T_LEN 8192
#define NSTEP 8190   // T - 2 interior samples
#define NB 16
#define NCH 256

// ---------------- threefry2x32 (exact JAX cipher) ----------------
__device__ __forceinline__ uint32_t rotl32(uint32_t v, int r) {
  return (v << r) | (v >> (32 - r));
}

__device__ __forceinline__ void tf2x32(uint32_t k0, uint32_t k1, uint32_t x0, uint32_t x1,
                                       uint32_t& o0, uint32_t& o1) {
  uint32_t ks2 = k0 ^ k1 ^ 0x1BD11BDAu;
  x0 += k0; x1 += k1;
#define RR(r) { x0 += x1; x1 = rotl32(x1, (r)); x1 ^= x0; }
  RR(13) RR(15) RR(26) RR(6)   x0 += k1;  x1 += ks2 + 1u;
  RR(17) RR(29) RR(16) RR(24)  x0 += ks2; x1 += k0 + 2u;
  RR(13) RR(15) RR(26) RR(6)   x0 += k0;  x1 += k1 + 3u;
  RR(17) RR(29) RR(16) RR(24)  x0 += k1;  x1 += ks2 + 4u;
  RR(13) RR(15) RR(26) RR(6)   x0 += ks2; x1 += k0 + 5u;
#undef RR
  o0 = x0; o1 = x1;
}

// ---------------- K1: per-step categorical decisions (VERIFIED r3) ----------
// PARTITIONABLE threefry semantics (JAX >= 0.4.36 default):
//   split(key, n)[i]          = full cipher pair threefry2x32(key, (hi32(i), lo32(i)))
//   random_bits(key,32,(m,))  = bits1 ^ bits2 of cipher(key, (0, c)), c = 0..m-1
// Record BOTH possible decisions: n (normal row), sp (special row (2,1)),
// packed as byte n | (sp<<2).
__global__ __launch_bounds__(256) void k_decide(const float* __restrict__ probs,
                                                uint8_t* __restrict__ dec) {
  int j = blockIdx.x * 256 + threadIdx.x;
  int b = blockIdx.y;
  if (j >= NSTEP) return;

  uint32_t kb0, kb1;
  tf2x32(0u, 42u, 0u, (uint32_t)b, kb0, kb1);      // split(key(42),16)[b]
  uint32_t s0, s1;
  tf2x32(kb0, kb1, 0u, (uint32_t)j, s0, s1);       // split(kb,8190)[j]

  uint32_t bits[3];
  {
    uint32_t y0, y1;
    tf2x32(s0, s1, 0u, 0u, y0, y1); bits[0] = y0 ^ y1;
    tf2x32(s0, s1, 0u, 1u, y0, y1); bits[1] = y0 ^ y1;
    tf2x32(s0, s1, 0u, 2u, y0, y1); bits[2] = y0 ^ y1;
  }

  double g[3];
#pragma unroll
  for (int c = 0; c < 3; ++c) {
    uint32_t k = bits[c] >> 9;                            // 23-bit mantissa sample
    float u = k ? (float)k * 0x1p-23f : 1.17549435e-38f;  // exact JAX uniform value
    g[c] = -log(-log((double)u));
  }

  double lp = log((double)probs[0]);
  double ls = log((double)probs[1]);
  double l1 = log((double)probs[2 * 9 + 1 * 3 + 1]);
  double l2 = log((double)probs[2 * 9 + 1 * 3 + 2]);

  double v0 = lp + g[0], v1 = ls + g[1], v2 = lp + g[2];
  int n = 0; double best = v0;
  if (v1 > best) { n = 1; best = v1; }
  if (v2 > best) { n = 2; }
  int sp = (l1 + g[1] >= l2 + g[2]) ? 1 : 2;

  dec[b * NSTEP + j] = (uint8_t)(n | (sp << 2));
}

// ---------------- K2: parallel Markov scan -> delta bytes (VERIFIED r4) ----
// State u = p2*3 + p1 in [0,9). Step: j = (u==7) ? spec : norm; u' = (u%3)*3 + j.
// Output: dbuf[b][t] = j in {0,1,2}; gather source = t + j - 1.
__device__ __forceinline__ uint64_t compose_map(uint64_t f, uint64_t g) {
  uint64_t r = 0;
#pragma unroll
  for (int st = 0; st < 9; ++st) {
    uint32_t fs = (uint32_t)((f >> (4 * st)) & 15u);
    uint32_t gs = (uint32_t)((g >> (4 * fs)) & 15u);
    r |= ((uint64_t)gs) << (4 * st);
  }
  return r;
}

__device__ __forceinline__ uint64_t shflup64(uint64_t v, int delta) {
  int lo = __shfl_up((int)(uint32_t)v, delta, 64);
  int hi = __shfl_up((int)(uint32_t)(v >> 32), delta, 64);
  return (((uint64_t)(uint32_t)hi) << 32) | (uint32_t)lo;
}

#define IDENT_MAP 0x876543210ull

__global__ __launch_bounds__(256) void k_scan(const uint8_t* __restrict__ dec,
                                              uint8_t* __restrict__ dbuf) {
  int b = blockIdx.x;
  int tid = threadIdx.x;
  int lane = tid & 63, wave = tid >> 6;
  int begin = tid * 32;
  const uint8_t* row = dec + b * NSTEP;

  // phase 1: build this chunk's 9-state map
  uint64_t M = IDENT_MAP;
#pragma unroll
  for (int t = 0; t < 32; ++t) {
    int step = begin + t;
    if (step < NSTEP) {
      int d = row[step];
      uint32_t n = d & 3u, s = (d >> 2) & 3u;
      uint64_t Mn = 0;
#pragma unroll
      for (int st = 0; st < 9; ++st) {
        uint32_t u = (uint32_t)((M >> (4 * st)) & 15u);
        uint32_t div3 = (u * 11u) >> 5;          // u/3 for u<9
        uint32_t p1 = u - 3u * div3;
        uint32_t jj = (u == 7u) ? s : n;
        Mn |= ((uint64_t)(p1 * 3u + jj)) << (4 * st);
      }
      M = Mn;
    }
  }

  // phase 2a: wave-inclusive scan
  uint64_t I = M;
#pragma unroll
  for (int off = 1; off < 64; off <<= 1) {
    uint64_t Mp = shflup64(I, off);
    uint64_t c = compose_map(Mp, I);
    I = (lane >= off) ? c : I;
  }

  __shared__ uint64_t wmap[4];
  if (lane == 63) wmap[wave] = I;
  __syncthreads();

  // phase 2b: exclusive prefix
  uint64_t W = IDENT_MAP;
  for (int w = 0; w < wave; ++w) W = compose_map(W, wmap[w]);
  uint64_t E = shflup64(I, 1);
  if (lane == 0) E = IDENT_MAP;
  uint64_t X = compose_map(W, E);

  int state = (int)((X >> (4 * 4)) & 15u);  // applied to initial chain state (1,1)=4

  // phase 3: replay chunk, emit delta bytes dbuf[b][step+1] = j
  uint8_t* orow = dbuf + b * T_LEN;
#pragma unroll
  for (int t = 0; t < 32; ++t) {
    int step = begin + t;
    if (step < NSTEP) {
      int d = row[step];
      uint32_t n = d & 3u, s = (d >> 2) & 3u;
      uint32_t jj = (state == 7) ? s : n;
      uint32_t div3 = ((uint32_t)state * 11u) >> 5;
      uint32_t p1 = (uint32_t)state - 3u * div3;
      state = (int)(p1 * 3u + jj);
      orow[step + 1] = (uint8_t)jj;
    }
  }
  if (tid == 0) { orow[0] = 1; orow[T_LEN - 1] = 1; }   // forced j=1 -> src=t
}

// ---------------- K3: copy-like shift-select gather (LDS halo) -------------
// out[b,i,t] = x[b,i,t+d-1], d in {0,1,2}.
// One block = one 4 KB row-chunk (b, i, tc). Per thread: exactly ONE float4
// load + ONE float4 store (+4 B dbuf, L2-hot). Halos via LDS neighbor
// exchange; block-edge values via 2 exec-masked scalar loads. blockIdx
// linear order sweeps contiguous memory (tc fastest, then i, then b) so the
// resident frontier is a dense 8 MB region, matching the copy/fill benches.
typedef float f32x4 __attribute__((ext_vector_type(4)));

__global__ __launch_bounds__(256) void k_gather(const float* __restrict__ x,
                                                const uint8_t* __restrict__ dbuf,
                                                float* __restrict__ out) {
  __shared__ float shx[256];   // each thread's v.x
  __shared__ float shw[256];   // each thread's v.w

  const int bid = blockIdx.x;
  const int tc = bid & 7;            // t-chunk (fastest -> contiguous sweep)
  const int i  = (bid >> 3) & 255;   // channel
  const int b  = bid >> 11;          // batch
  const int tid = threadIdx.x;
  const int t0 = tc * 1024 + tid * 4;

  const uchar4 du = *(const uchar4*)(dbuf + b * T_LEN + t0);
  const float* __restrict__ xr = x + ((size_t)(b * NCH + i)) * T_LEN;

  float4 v = *(const float4*)(xr + t0);

  // block-edge halos (clamped at array ends; forced d=1 there => never selected)
  float Le = 0.0f, Re = 0.0f;
  if (tid == 0)   Le = (t0 > 0) ? xr[t0 - 1] : 0.0f;
  if (tid == 255) Re = (t0 + 4 < T_LEN) ? xr[t0 + 4] : 0.0f;

  shx[tid] = v.x;
  shw[tid] = v.w;
  __syncthreads();

  const float L = (tid == 0)   ? Le : shw[tid - 1];
  const float R = (tid == 255) ? Re : shx[tid + 1];

  f32x4 o;
  o.x = (du.x == 0) ? L   : ((du.x == 1) ? v.x : v.y);
  o.y = (du.y == 0) ? v.x : ((du.y == 1) ? v.y : v.z);
  o.z = (du.z == 0) ? v.y : ((du.z == 1) ? v.z : v.w);
  o.w = (du.w == 0) ? v.z : ((du.w == 1) ? v.w : R);
  __builtin_nontemporal_store(o, (f32x4*)(out + ((size_t)(b * NCH + i)) * T_LEN + t0));
}

extern "C" void kernel_launch(void* const* d_in, const int* in_sizes, int n_in,
                              void* d_out, int out_size, void* d_ws, size_t ws_size,
                              hipStream_t stream) {
  const float* x = (const float*)d_in[0];
  const float* probs = (const float*)d_in[1];
  float* out = (float*)d_out;

  uint8_t* dec = (uint8_t*)d_ws;                       // 16*8190 = 131040 B
  uint8_t* dbuf = (uint8_t*)d_ws + 131072;             // 16*8192 = 128 KiB

  dim3 g1((NSTEP + 255) / 256, NB);
  k_decide<<<g1, 256, 0, stream>>>(probs, dec);

  k_scan<<<NB, 256, 0, stream>>>(dec, dbuf);

  // 16 batches * 256 channels * 8 t-chunks = 32768 blocks, linear
  k_gather<<<NB * NCH * 8, 256, 0, stream>>>(x, dbuf, out);
}